// Round 3
// baseline (61.723 us; speedup 1.0000x reference)
//
#include <hip/hip_runtime.h>

// QuantumVelocityField: fused 4->128->128->6 silu MLP (fp16 MFMA, fp32 accum)
// + 3-layer RY/RZ single-qubit sim. B = 262144.
//
// R3 = R2 with compile fix (cvt_pkrtz returns __fp16x2 -> bit_cast to half2).
// R2 changes vs R1 (theory: VALU/occupancy-bound, Occ 17.7%, VALUBusy 62%):
//  - grid 512x4tiles -> 1024x2tiles, __launch_bounds__(256,4): 4 blocks/CU
//    resident (LDS 39.9KB), 16 waves/CU.
//  - W2 permute+swizzle+fp16 moved to a pre-pack kernel into d_ws; main
//    kernel stages the final LDS image with a linear half8 copy.
//  - packed v_cvt_pkrtz for fp32->fp16 epilogues.
//  - sP bounce is wave-private: __syncthreads replaced by lgkmcnt(0) fences.
//  - output coalesced via small LDS bounce (dwordx2 stores, 48 lanes).

typedef _Float16 half8 __attribute__((ext_vector_type(8)));
typedef _Float16 half2 __attribute__((ext_vector_type(2)));
typedef float f32x4 __attribute__((ext_vector_type(4)));
typedef float f32x2 __attribute__((ext_vector_type(2)));

#define TILES_PER_BLOCK 2
#define NBLOCKS 1024  // 1024*2 tiles * 128 rows = 262144

union Half8U { half8 v; half2 h2[4]; };

__device__ __forceinline__ half2 silu2(float x0, float x1) {
    float s0 = __fdividef(x0, 1.0f + __expf(-x0));
    float s1 = __fdividef(x1, 1.0f + __expf(-x1));
    return __builtin_bit_cast(half2, __builtin_amdgcn_cvt_pkrtz(s0, s1));
}

// Pre-pack W2: [k][n2] f32 -> permuted (k' = 32s+8q+4hi+c) + XOR-swizzled
// fp16 image, exactly the LDS layout the main kernel consumes.
__global__ void qvf_pack(const float* __restrict__ W2g, _Float16* __restrict__ dst) {
    int i = blockIdx.x * 256 + threadIdx.x;   // 0..16383, coalesced read
    int k = i >> 7, n2 = i & 127;
    float wv = W2g[i];
    int s = k >> 5, hi = (k >> 4) & 1, qq = (k >> 2) & 3, c = k & 3;
    int kp = s * 32 + qq * 8 + hi * 4 + c;
    dst[n2 * 128 + (kp ^ ((n2 & 7) << 3))] = (_Float16)wv;
}

template <bool PREPACK>
__global__ __launch_bounds__(256, 4)
void qvf_kernel(const float* __restrict__ tg, const float* __restrict__ blg,
                const float* __restrict__ W1g, const float* __restrict__ b1g,
                const float* __restrict__ W2g, const float* __restrict__ b2g,
                const float* __restrict__ W3g, const float* __restrict__ b3g,
                const _Float16* __restrict__ ws2,
                float* __restrict__ out) {
    __shared__ __align__(16) _Float16 sW2p[16384];
    __shared__ __align__(16) float sB1[128];
    __shared__ __align__(16) float sB2[128];
    __shared__ float sP[4][32][9];   // per-wave param bounce, stride 9
    __shared__ __align__(8) float sO[4][96];  // per-wave output bounce

    const int tid  = threadIdx.x;
    const int w    = tid >> 6;
    const int lane = tid & 63;
    const int q    = lane >> 4;
    const int ln   = lane & 15;

    // ---- stage W2 image and biases ----
    if (PREPACK) {
        #pragma unroll
        for (int i = 0; i < 8; ++i) {
            int j = (i * 256 + tid) * 8;
            *(half8*)&sW2p[j] = *(const half8*)&ws2[j];
        }
    } else {
        for (int i = tid; i < 16384; i += 256) {
            int k = i >> 7, n2 = i & 127;
            float wv = W2g[i];
            int s = k >> 5, hi = (k >> 4) & 1, qq = (k >> 2) & 3, c = k & 3;
            int kp = s * 32 + qq * 8 + hi * 4 + c;
            sW2p[n2 * 128 + (kp ^ ((n2 & 7) << 3))] = (_Float16)wv;
        }
    }
    if (tid < 128) { sB1[tid] = b1g[tid]; sB2[tid] = b2g[tid]; }

    // ---- per-lane cached weight fragments (reused for all tiles) ----
    half8 W1c[8];
    #pragma unroll
    for (int nt = 0; nt < 8; ++nt) {
        half8 v = {};
        if (q == 0) {
            int n1 = nt * 16 + ln;
            #pragma unroll
            for (int j = 0; j < 4; ++j) v[j] = (_Float16)W1g[j * 128 + n1];
        }
        W1c[nt] = v;
    }
    half8 W3c[4];
    #pragma unroll
    for (int s = 0; s < 4; ++s) {
        half8 v = {};
        if (ln < 6) {
            #pragma unroll
            for (int j = 0; j < 8; ++j) {
                int k = s * 32 + (j >> 2) * 16 + q * 4 + (j & 3);
                v[j] = (_Float16)W3g[k * 6 + ln];
            }
        }
        W3c[s] = v;
    }
    float b3c[4];
    #pragma unroll
    for (int r = 0; r < 4; ++r) {
        int n3 = q * 4 + r;
        b3c[r] = (n3 < 6) ? b3g[n3] : 0.0f;
    }

    __syncthreads();

    #pragma unroll 1
    for (int tt = 0; tt < TILES_PER_BLOCK; ++tt) {
        const int tile = blockIdx.x * TILES_PER_BLOCK + tt;
        const int rowb = tile * 128 + w * 32;   // this wave's 32 batch rows

        // ---- layer-1 B fragments: inp = [t, bloch] in k-slots 0..3 (q==0) ----
        half8 bf1[2] = {{}, {}};
        if (q == 0) {
            #pragma unroll
            for (int mt = 0; mt < 2; ++mt) {
                int m = rowb + mt * 16 + ln;
                bf1[mt][0] = (_Float16)tg[m];
                bf1[mt][1] = (_Float16)blg[3 * m + 0];
                bf1[mt][2] = (_Float16)blg[3 * m + 1];
                bf1[mt][3] = (_Float16)blg[3 * m + 2];
            }
        }

        // ---- layer 1: D1[n1][m] ----
        f32x4 acc1[2][8];
        #pragma unroll
        for (int nt = 0; nt < 8; ++nt) {
            acc1[0][nt] = __builtin_amdgcn_mfma_f32_16x16x32_f16(W1c[nt], bf1[0], (f32x4){0.f,0.f,0.f,0.f}, 0, 0, 0);
            acc1[1][nt] = __builtin_amdgcn_mfma_f32_16x16x32_f16(W1c[nt], bf1[1], (f32x4){0.f,0.f,0.f,0.f}, 0, 0, 0);
        }

        // ---- epilogue 1: bias + silu -> layer-2 B frags (in-register) ----
        half8 bf2[2][4];
        #pragma unroll
        for (int mt = 0; mt < 2; ++mt) {
            #pragma unroll
            for (int s = 0; s < 4; ++s) {
                Half8U u;
                #pragma unroll
                for (int hj = 0; hj < 2; ++hj) {
                    int nt = 2 * s + hj;
                    f32x4 bb = *(const f32x4*)&sB1[nt * 16 + 4 * q];
                    u.h2[hj * 2 + 0] = silu2(acc1[mt][nt][0] + bb[0], acc1[mt][nt][1] + bb[1]);
                    u.h2[hj * 2 + 1] = silu2(acc1[mt][nt][2] + bb[2], acc1[mt][nt][3] + bb[3]);
                }
                bf2[mt][s] = u.v;
            }
        }

        // ---- layer 2: D2[n2][m], A from LDS ----
        f32x4 acc2[2][8];
        #pragma unroll
        for (int mt = 0; mt < 2; ++mt)
            #pragma unroll
            for (int nt = 0; nt < 8; ++nt)
                acc2[mt][nt] = (f32x4){0.f, 0.f, 0.f, 0.f};
        #pragma unroll
        for (int s = 0; s < 4; ++s) {
            #pragma unroll
            for (int nt = 0; nt < 8; ++nt) {
                int n2 = nt * 16 + ln;
                int hw = n2 * 128 + ((s * 32 + q * 8) ^ ((n2 & 7) << 3));
                half8 a2 = *(const half8*)&sW2p[hw];
                acc2[0][nt] = __builtin_amdgcn_mfma_f32_16x16x32_f16(a2, bf2[0][s], acc2[0][nt], 0, 0, 0);
                acc2[1][nt] = __builtin_amdgcn_mfma_f32_16x16x32_f16(a2, bf2[1][s], acc2[1][nt], 0, 0, 0);
            }
        }

        // ---- epilogue 2: bias + silu -> layer-3 B frags ----
        half8 bf3[2][4];
        #pragma unroll
        for (int mt = 0; mt < 2; ++mt) {
            #pragma unroll
            for (int s = 0; s < 4; ++s) {
                Half8U u;
                #pragma unroll
                for (int hj = 0; hj < 2; ++hj) {
                    int nt = 2 * s + hj;
                    f32x4 bb = *(const f32x4*)&sB2[nt * 16 + 4 * q];
                    u.h2[hj * 2 + 0] = silu2(acc2[mt][nt][0] + bb[0], acc2[mt][nt][1] + bb[1]);
                    u.h2[hj * 2 + 1] = silu2(acc2[mt][nt][2] + bb[2], acc2[mt][nt][3] + bb[3]);
                }
                bf3[mt][s] = u.v;
            }
        }

        // ---- layer 3: p^T[n3][m], n3 = 0..5 valid ----
        f32x4 acc3[2];
        acc3[0] = (f32x4){0.f, 0.f, 0.f, 0.f};
        acc3[1] = (f32x4){0.f, 0.f, 0.f, 0.f};
        #pragma unroll
        for (int s = 0; s < 4; ++s) {
            acc3[0] = __builtin_amdgcn_mfma_f32_16x16x32_f16(W3c[s], bf3[0][s], acc3[0], 0, 0, 0);
            acc3[1] = __builtin_amdgcn_mfma_f32_16x16x32_f16(W3c[s], bf3[1][s], acc3[1], 0, 0, 0);
        }

        // ---- epilogue 3: params -> wave-private LDS bounce ----
        #pragma unroll
        for (int mt = 0; mt < 2; ++mt) {
            #pragma unroll
            for (int r = 0; r < 4; ++r) {
                int n3 = 4 * q + r;
                if (n3 < 6) sP[w][mt * 16 + ln][n3] = acc3[mt][r] + b3c[r];
            }
        }
        // wave-private: lgkmcnt drain + compiler fence instead of __syncthreads
        asm volatile("s_waitcnt lgkmcnt(0)" ::: "memory");
        __builtin_amdgcn_wave_barrier();

        // ---- quantum circuit sim: lanes 0..31, one batch row each ----
        if (lane < 32) {
            const float* pr = &sP[w][lane][0];
            float ar = 1.f, ai = 0.f, br = 0.f, bi = 0.f;
            #pragma unroll
            for (int l = 0; l < 3; ++l) {
                float th = pr[2 * l] * 0.5f;
                float ph = pr[2 * l + 1] * 0.5f;
                float s1, c1, se, ce;
                __sincosf(th, &s1, &c1);
                float a1r = c1 * ar - s1 * br, a1i = c1 * ai - s1 * bi;
                float b1r = s1 * ar + c1 * br, b1i = s1 * ai + c1 * bi;
                __sincosf(ph, &se, &ce);
                ar = ce * a1r + se * a1i; ai = ce * a1i - se * a1r;
                br = ce * b1r - se * b1i; bi = ce * b1i + se * b1r;
            }
            float* po = &sO[w][3 * lane];
            po[0] = 2.f * (ar * br + ai * bi);
            po[1] = 2.f * (ar * bi - ai * br);
            po[2] = ar * ar + ai * ai - br * br - bi * bi;
        }
        asm volatile("s_waitcnt lgkmcnt(0)" ::: "memory");
        __builtin_amdgcn_wave_barrier();

        // ---- coalesced output: 96 floats per wave as 48 dwordx2 ----
        if (lane < 48) {
            f32x2 vv = *(const f32x2*)&sO[w][2 * lane];
            *(f32x2*)&out[3 * rowb + 2 * lane] = vv;
        }
        asm volatile("s_waitcnt lgkmcnt(0)" ::: "memory");
        __builtin_amdgcn_wave_barrier();
    }
}

extern "C" void kernel_launch(void* const* d_in, const int* in_sizes, int n_in,
                              void* d_out, int out_size, void* d_ws, size_t ws_size,
                              hipStream_t stream) {
    const float* t  = (const float*)d_in[0];
    const float* bl = (const float*)d_in[1];
    const float* W1 = (const float*)d_in[2];
    const float* b1 = (const float*)d_in[3];
    const float* W2 = (const float*)d_in[4];
    const float* b2 = (const float*)d_in[5];
    const float* W3 = (const float*)d_in[6];
    const float* b3 = (const float*)d_in[7];
    float* out = (float*)d_out;

    if (ws_size >= 16384 * sizeof(_Float16)) {
        _Float16* ws2 = (_Float16*)d_ws;
        qvf_pack<<<64, 256, 0, stream>>>(W2, ws2);
        qvf_kernel<true><<<NBLOCKS, 256, 0, stream>>>(t, bl, W1, b1, W2, b2, W3, b3, ws2, out);
    } else {
        qvf_kernel<false><<<NBLOCKS, 256, 0, stream>>>(t, bl, W1, b1, W2, b2, W3, b3, nullptr, out);
    }
}

// Round 4
// 48.440 us; speedup vs baseline: 1.2742x; 1.2742x over previous
//
#include <hip/hip_runtime.h>

// QuantumVelocityField: fused 4->128->128->6 silu MLP (fp16 MFMA, fp32 accum)
// + 3-layer RY/RZ single-qubit sim. B = 262144.
//
// R4: fix R3's spill catastrophe (launch_bounds(256,4) -> 64 VGPR cap -> 90MB
// scratch traffic). Changes:
//  - __launch_bounds__(256,3): VGPR cap 168, no spills; grid 1024 x 2 tiles.
//  - pack kernel emits ONE 36864B image (W2 swizzled, W1/W3 fragment layouts,
//    biases); main kernel stages it with 9 linear dwordx4 copies.
//  - W1/W3 fragments read from LDS per tile instead of living in registers
//    (frees ~48 long-lived VGPRs).
//  - sP param bounce: stride-8 rows + rotation swizzle (col+row)&7.
//  - LDS total exactly 40960B -> 4 blocks/CU if VGPR <= 128, else 3.

typedef _Float16 half8 __attribute__((ext_vector_type(8)));
typedef _Float16 half4 __attribute__((ext_vector_type(4)));
typedef _Float16 half2 __attribute__((ext_vector_type(2)));
typedef float f32x4 __attribute__((ext_vector_type(4)));
typedef float f32x2 __attribute__((ext_vector_type(2)));

#define TILES_PER_BLOCK 2
#define NBLOCKS 1024          // 1024 * 2 tiles * 128 rows = 262144
#define WS_IMG_BYTES 36864    // 9 * 256 threads * 16B

union Half8U { half8 v; half2 h2[4]; };

__device__ __forceinline__ half2 silu2(float x0, float x1) {
    float s0 = __fdividef(x0, 1.0f + __expf(-x0));
    float s1 = __fdividef(x1, 1.0f + __expf(-x1));
    return __builtin_bit_cast(half2, __builtin_amdgcn_cvt_pkrtz(s0, s1));
}

#define DSFENCE() do { asm volatile("s_waitcnt lgkmcnt(0)" ::: "memory"); \
                       __builtin_amdgcn_wave_barrier(); } while (0)

// ---------------------------------------------------------------------------
// Pack kernel: build the full LDS image in d_ws.
//   halfs [0,16384)        : W2 permuted (k'=32s+8q+4hi+c) + XOR swizzle
//   halfs [16384,16896)    : W1 frags  [nt][ln][4]  (val = W1[j][nt*16+ln])
//   halfs [16896,17664)    : W3 frags  [s][ln<6][q][8]
//   floats[8832,8960)      : b1
//   floats[8960,9088)      : b2
//   floats[9088,9094)      : b3   (+ zero pad to float 9216)
// ---------------------------------------------------------------------------
__global__ void qvf_pack(const float* __restrict__ W1g, const float* __restrict__ b1g,
                         const float* __restrict__ W2g, const float* __restrict__ b2g,
                         const float* __restrict__ W3g, const float* __restrict__ b3g,
                         unsigned char* __restrict__ ws) {
    _Float16* h = (_Float16*)ws;
    float*    f = (float*)ws;
    const int b = blockIdx.x, tid = threadIdx.x;
    if (b < 64) {
        int i = b * 256 + tid;                 // 0..16383, coalesced read
        int k = i >> 7, n2 = i & 127;
        float wv = W2g[i];
        int s = k >> 5, hi = (k >> 4) & 1, qq = (k >> 2) & 3, c = k & 3;
        int kp = s * 32 + qq * 8 + hi * 4 + c;
        h[n2 * 128 + (kp ^ ((n2 & 7) << 3))] = (_Float16)wv;
    } else {
        for (int i = tid; i < 512; i += 256) {          // W1 frags
            int j = i & 3, ln = (i >> 2) & 15, nt = i >> 6;
            h[16384 + i] = (_Float16)W1g[j * 128 + nt * 16 + ln];
        }
        for (int i = tid; i < 768; i += 256) {          // W3 frags
            int j = i & 7, t2 = i >> 3;
            int q = t2 & 3, u = t2 >> 2;
            int ln = u % 6, s = u / 6;
            int k = s * 32 + ((j >> 2) << 4) + q * 4 + (j & 3);
            h[16896 + i] = (_Float16)W3g[k * 6 + ln];
        }
        if (tid < 128) { f[8832 + tid] = b1g[tid]; f[8960 + tid] = b2g[tid]; }
        if (tid < 6)   { f[9088 + tid] = b3g[tid]; }
        for (int i = 9094 + tid; i < 9216; i += 256) f[i] = 0.f;  // pad
    }
}

// ---------------------------------------------------------------------------
template <bool PREPACK>
__global__ __launch_bounds__(256, 3)
void qvf_kernel(const float* __restrict__ tg, const float* __restrict__ blg,
                const float* __restrict__ W1g, const float* __restrict__ b1g,
                const float* __restrict__ W2g, const float* __restrict__ b2g,
                const float* __restrict__ W3g, const float* __restrict__ b3g,
                const unsigned char* __restrict__ ws,
                float* __restrict__ out) {
    __shared__ __align__(16) unsigned char sRaw[40960];
    _Float16*    sW2 = (_Float16*)sRaw;
    _Float16*    sW1 = (_Float16*)(sRaw + 32768);
    _Float16*    sW3 = (_Float16*)(sRaw + 33792);
    const float* sB1 = (const float*)(sRaw + 35328);
    const float* sB2 = (const float*)(sRaw + 35840);
    float*       sP  = (float*)(sRaw + 36864);   // [4 waves][32 rows][8] rotated

    const int tid  = threadIdx.x;
    const int w    = tid >> 6;
    const int lane = tid & 63;
    const int q    = lane >> 4;
    const int ln   = lane & 15;

    // ---- stage the weight image ----
    if (PREPACK) {
        #pragma unroll
        for (int i = 0; i < 9; ++i) {
            int off = (i * 256 + tid) * 16;
            *(f32x4*)(sRaw + off) = *(const f32x4*)(ws + off);
        }
    } else {
        _Float16* h = (_Float16*)sRaw;
        float*    f = (float*)sRaw;
        for (int i = tid; i < 16384; i += 256) {
            int k = i >> 7, n2 = i & 127;
            float wv = W2g[i];
            int s = k >> 5, hi = (k >> 4) & 1, qq = (k >> 2) & 3, c = k & 3;
            int kp = s * 32 + qq * 8 + hi * 4 + c;
            h[n2 * 128 + (kp ^ ((n2 & 7) << 3))] = (_Float16)wv;
        }
        for (int i = tid; i < 512; i += 256) {
            int j = i & 3, l2 = (i >> 2) & 15, nt = i >> 6;
            h[16384 + i] = (_Float16)W1g[j * 128 + nt * 16 + l2];
        }
        for (int i = tid; i < 768; i += 256) {
            int j = i & 7, t2 = i >> 3;
            int q2 = t2 & 3, u = t2 >> 2;
            int l2 = u % 6, s = u / 6;
            int k = s * 32 + ((j >> 2) << 4) + q2 * 4 + (j & 3);
            h[16896 + i] = (_Float16)W3g[k * 6 + l2];
        }
        if (tid < 128) { f[8832 + tid] = b1g[tid]; f[8960 + tid] = b2g[tid]; }
    }
    // b3 per-lane regs (4 regs, loaded once from global)
    float b3c[4];
    #pragma unroll
    for (int r = 0; r < 4; ++r) {
        int n3 = 4 * q + r;
        b3c[r] = (n3 < 6) ? b3g[n3] : 0.0f;
    }

    __syncthreads();

    float* sPW = sP + w * 256;   // this wave's 32x8 param rows

    #pragma unroll 1
    for (int tt = 0; tt < TILES_PER_BLOCK; ++tt) {
        const int tile = blockIdx.x * TILES_PER_BLOCK + tt;
        const int rowb = tile * 128 + w * 32;

        // ---- layer-1 B fragments: inp = [t, bloch] in k-slots 0..3 (q==0) ----
        half8 bf1[2] = {{}, {}};
        if (q == 0) {
            #pragma unroll
            for (int mt = 0; mt < 2; ++mt) {
                int m = rowb + mt * 16 + ln;
                bf1[mt][0] = (_Float16)tg[m];
                bf1[mt][1] = (_Float16)blg[3 * m + 0];
                bf1[mt][2] = (_Float16)blg[3 * m + 1];
                bf1[mt][3] = (_Float16)blg[3 * m + 2];
            }
        }

        // ---- layer 1: A-frags from LDS ----
        f32x4 acc1[2][8];
        #pragma unroll
        for (int nt = 0; nt < 8; ++nt) {
            half8 a1 = {};
            if (q == 0) {
                half4 lo = *(const half4*)&sW1[nt * 64 + ln * 4];
                a1[0] = lo[0]; a1[1] = lo[1]; a1[2] = lo[2]; a1[3] = lo[3];
            }
            acc1[0][nt] = __builtin_amdgcn_mfma_f32_16x16x32_f16(a1, bf1[0], (f32x4){0.f,0.f,0.f,0.f}, 0, 0, 0);
            acc1[1][nt] = __builtin_amdgcn_mfma_f32_16x16x32_f16(a1, bf1[1], (f32x4){0.f,0.f,0.f,0.f}, 0, 0, 0);
        }

        // ---- epilogue 1: bias + silu -> layer-2 B frags ----
        half8 bf2[2][4];
        #pragma unroll
        for (int mt = 0; mt < 2; ++mt) {
            #pragma unroll
            for (int s = 0; s < 4; ++s) {
                Half8U u;
                #pragma unroll
                for (int hj = 0; hj < 2; ++hj) {
                    int nt = 2 * s + hj;
                    f32x4 bb = *(const f32x4*)&sB1[nt * 16 + 4 * q];
                    u.h2[hj * 2 + 0] = silu2(acc1[mt][nt][0] + bb[0], acc1[mt][nt][1] + bb[1]);
                    u.h2[hj * 2 + 1] = silu2(acc1[mt][nt][2] + bb[2], acc1[mt][nt][3] + bb[3]);
                }
                bf2[mt][s] = u.v;
            }
        }

        // ---- layer 2: A from LDS (swizzled) ----
        f32x4 acc2[2][8];
        #pragma unroll
        for (int mt = 0; mt < 2; ++mt)
            #pragma unroll
            for (int nt = 0; nt < 8; ++nt)
                acc2[mt][nt] = (f32x4){0.f, 0.f, 0.f, 0.f};
        #pragma unroll
        for (int s = 0; s < 4; ++s) {
            #pragma unroll
            for (int nt = 0; nt < 8; ++nt) {
                int n2 = nt * 16 + ln;
                int hw = n2 * 128 + ((s * 32 + q * 8) ^ ((n2 & 7) << 3));
                half8 a2 = *(const half8*)&sW2[hw];
                acc2[0][nt] = __builtin_amdgcn_mfma_f32_16x16x32_f16(a2, bf2[0][s], acc2[0][nt], 0, 0, 0);
                acc2[1][nt] = __builtin_amdgcn_mfma_f32_16x16x32_f16(a2, bf2[1][s], acc2[1][nt], 0, 0, 0);
            }
        }

        // ---- epilogue 2: bias + silu -> layer-3 B frags ----
        half8 bf3[2][4];
        #pragma unroll
        for (int mt = 0; mt < 2; ++mt) {
            #pragma unroll
            for (int s = 0; s < 4; ++s) {
                Half8U u;
                #pragma unroll
                for (int hj = 0; hj < 2; ++hj) {
                    int nt = 2 * s + hj;
                    f32x4 bb = *(const f32x4*)&sB2[nt * 16 + 4 * q];
                    u.h2[hj * 2 + 0] = silu2(acc2[mt][nt][0] + bb[0], acc2[mt][nt][1] + bb[1]);
                    u.h2[hj * 2 + 1] = silu2(acc2[mt][nt][2] + bb[2], acc2[mt][nt][3] + bb[3]);
                }
                bf3[mt][s] = u.v;
            }
        }

        // ---- layer 3: A-frags from LDS ----
        f32x4 acc3[2];
        acc3[0] = (f32x4){0.f, 0.f, 0.f, 0.f};
        acc3[1] = (f32x4){0.f, 0.f, 0.f, 0.f};
        #pragma unroll
        for (int s = 0; s < 4; ++s) {
            half8 a3 = {};
            if (ln < 6) a3 = *(const half8*)&sW3[((s * 6 + ln) * 4 + q) * 8];
            acc3[0] = __builtin_amdgcn_mfma_f32_16x16x32_f16(a3, bf3[0][s], acc3[0], 0, 0, 0);
            acc3[1] = __builtin_amdgcn_mfma_f32_16x16x32_f16(a3, bf3[1][s], acc3[1], 0, 0, 0);
        }

        // ---- epilogue 3: params -> rotated stride-8 rows ----
        #pragma unroll
        for (int mt = 0; mt < 2; ++mt) {
            #pragma unroll
            for (int r = 0; r < 4; ++r) {
                int n3 = 4 * q + r;
                if (n3 < 6) {
                    int row = mt * 16 + ln;
                    sPW[row * 8 + ((n3 + row) & 7)] = acc3[mt][r] + b3c[r];
                }
            }
        }
        DSFENCE();   // wave-private cross-lane visibility

        // ---- circuit sim: lanes 0..31, one batch row each ----
        float o0 = 0.f, o1 = 0.f, o2 = 0.f;
        if (lane < 32) {
            float pr[6];
            #pragma unroll
            for (int j = 0; j < 6; ++j) pr[j] = sPW[lane * 8 + ((j + lane) & 7)];
            float ar = 1.f, ai = 0.f, br = 0.f, bi = 0.f;
            #pragma unroll
            for (int l = 0; l < 3; ++l) {
                float th = pr[2 * l] * 0.5f;
                float ph = pr[2 * l + 1] * 0.5f;
                float s1, c1, se, ce;
                __sincosf(th, &s1, &c1);
                float a1r = c1 * ar - s1 * br, a1i = c1 * ai - s1 * bi;
                float b1r = s1 * ar + c1 * br, b1i = s1 * ai + c1 * bi;
                __sincosf(ph, &se, &ce);
                ar = ce * a1r + se * a1i; ai = ce * a1i - se * a1r;
                br = ce * b1r - se * b1i; bi = ce * b1i + se * b1r;
            }
            o0 = 2.f * (ar * br + ai * bi);
            o1 = 2.f * (ar * bi - ai * br);
            o2 = ar * ar + ai * ai - br * br - bi * bi;
        }
        DSFENCE();   // all param reads complete before overwrite

        if (lane < 32) {   // dense 96-float output bounce (banks 3l mod 32: conflict-free)
            sPW[3 * lane + 0] = o0;
            sPW[3 * lane + 1] = o1;
            sPW[3 * lane + 2] = o2;
        }
        DSFENCE();

        if (lane < 48) {   // coalesced dwordx2 stores
            f32x2 vv = *(const f32x2*)&sPW[2 * lane];
            *(f32x2*)&out[3 * rowb + 2 * lane] = vv;
        }
        DSFENCE();   // dense reads complete before next tile's param writes
    }
}

extern "C" void kernel_launch(void* const* d_in, const int* in_sizes, int n_in,
                              void* d_out, int out_size, void* d_ws, size_t ws_size,
                              hipStream_t stream) {
    const float* t  = (const float*)d_in[0];
    const float* bl = (const float*)d_in[1];
    const float* W1 = (const float*)d_in[2];
    const float* b1 = (const float*)d_in[3];
    const float* W2 = (const float*)d_in[4];
    const float* b2 = (const float*)d_in[5];
    const float* W3 = (const float*)d_in[6];
    const float* b3 = (const float*)d_in[7];
    float* out = (float*)d_out;

    if (ws_size >= WS_IMG_BYTES) {
        unsigned char* ws = (unsigned char*)d_ws;
        qvf_pack<<<65, 256, 0, stream>>>(W1, b1, W2, b2, W3, b3, ws);
        qvf_kernel<true><<<NBLOCKS, 256, 0, stream>>>(t, bl, W1, b1, W2, b2, W3, b3, ws, out);
    } else {
        qvf_kernel<false><<<NBLOCKS, 256, 0, stream>>>(t, bl, W1, b1, W2, b2, W3, b3, nullptr, out);
    }
}

// Round 5
// 45.862 us; speedup vs baseline: 1.3458x; 1.0562x over previous
//
#include <hip/hip_runtime.h>

// QuantumVelocityField: fused 4->128->128->6 silu MLP (fp16 MFMA, fp32 accum)
// + 3-layer RY/RZ single-qubit sim. B = 262144.
//
// R5 vs R4 (VALU-bound, VALUBusy 70%):
//  - bias folded into MFMA C-operand init (no epilogue adds, no zero-movs).
//  - circuit deferred: both tiles' params packed fp16 into LDS (stride-3
//    dwords, conflict-free), ONE full-wave 64-row circuit phase (was 2x
//    half-idle). Fences 8 -> 2 per tile-pair.
//  - LDS 39936B, 4 blocks/CU; __launch_bounds__(256,3); grid 1024 x 2 tiles.

typedef _Float16 half8 __attribute__((ext_vector_type(8)));
typedef _Float16 half4 __attribute__((ext_vector_type(4)));
typedef _Float16 half2 __attribute__((ext_vector_type(2)));
typedef float f32x4 __attribute__((ext_vector_type(4)));
typedef float f32x2 __attribute__((ext_vector_type(2)));

#define NBLOCKS 1024          // 1024 blocks * 2 tiles * 128 rows = 262144
#define WS_IMG_BYTES 36864    // 9 * 256 threads * 16B

union Half8U { half8 v; half2 h2[4]; };

__device__ __forceinline__ half2 silu2(float x0, float x1) {
    float s0 = __fdividef(x0, 1.0f + __expf(-x0));
    float s1 = __fdividef(x1, 1.0f + __expf(-x1));
    return __builtin_bit_cast(half2, __builtin_amdgcn_cvt_pkrtz(s0, s1));
}
__device__ __forceinline__ unsigned int pk16(float x0, float x1) {
    return __builtin_bit_cast(unsigned int, __builtin_amdgcn_cvt_pkrtz(x0, x1));
}

#define DSFENCE() do { asm volatile("s_waitcnt lgkmcnt(0)" ::: "memory"); \
                       __builtin_amdgcn_wave_barrier(); } while (0)

// ---------------------------------------------------------------------------
// Pack kernel: build the LDS image in d_ws (identical layout to R4).
//   halfs [0,16384)     : W2 permuted (k'=32s+8q+4hi+c) + XOR swizzle
//   halfs [16384,16896) : W1 frags [nt][ln][4]
//   halfs [16896,17664) : W3 frags [s][ln<6][q][8]
//   floats[8832,8960)   : b1 ; floats[8960,9088) : b2 ; rest pad
// ---------------------------------------------------------------------------
__global__ void qvf_pack(const float* __restrict__ W1g, const float* __restrict__ b1g,
                         const float* __restrict__ W2g, const float* __restrict__ b2g,
                         const float* __restrict__ W3g, const float* __restrict__ b3g,
                         unsigned char* __restrict__ ws) {
    _Float16* h = (_Float16*)ws;
    float*    f = (float*)ws;
    const int b = blockIdx.x, tid = threadIdx.x;
    if (b < 64) {
        int i = b * 256 + tid;
        int k = i >> 7, n2 = i & 127;
        float wv = W2g[i];
        int s = k >> 5, hi = (k >> 4) & 1, qq = (k >> 2) & 3, c = k & 3;
        int kp = s * 32 + qq * 8 + hi * 4 + c;
        h[n2 * 128 + (kp ^ ((n2 & 7) << 3))] = (_Float16)wv;
    } else {
        for (int i = tid; i < 512; i += 256) {
            int j = i & 3, ln = (i >> 2) & 15, nt = i >> 6;
            h[16384 + i] = (_Float16)W1g[j * 128 + nt * 16 + ln];
        }
        for (int i = tid; i < 768; i += 256) {
            int j = i & 7, t2 = i >> 3;
            int q = t2 & 3, u = t2 >> 2;
            int ln = u % 6, s = u / 6;
            int k = s * 32 + ((j >> 2) << 4) + q * 4 + (j & 3);
            h[16896 + i] = (_Float16)W3g[k * 6 + ln];
        }
        if (tid < 128) { f[8832 + tid] = b1g[tid]; f[8960 + tid] = b2g[tid]; }
        for (int i = 9088 + tid; i < 9216; i += 256) f[i] = 0.f;
    }
}

// ---------------------------------------------------------------------------
template <bool PREPACK>
__global__ __launch_bounds__(256, 3)
void qvf_kernel(const float* __restrict__ tg, const float* __restrict__ blg,
                const float* __restrict__ W1g, const float* __restrict__ b1g,
                const float* __restrict__ W2g, const float* __restrict__ b2g,
                const float* __restrict__ W3g, const float* __restrict__ b3g,
                const unsigned char* __restrict__ ws,
                float* __restrict__ out) {
    __shared__ __align__(16) unsigned char sRaw[39936];
    _Float16*    sW2 = (_Float16*)sRaw;
    _Float16*    sW1 = (_Float16*)(sRaw + 32768);
    _Float16*    sW3 = (_Float16*)(sRaw + 33792);
    const float* sB1 = (const float*)(sRaw + 35328);
    const float* sB2 = (const float*)(sRaw + 35840);

    const int tid  = threadIdx.x;
    const int w    = tid >> 6;
    const int lane = tid & 63;
    const int q    = lane >> 4;
    const int ln   = lane & 15;

    unsigned int* sPU = (unsigned int*)(sRaw + 36864) + w * 192;  // 64 rows x 3 dwords
    float*        sPF = (float*)sPU;

    // ---- stage the weight image ----
    if (PREPACK) {
        #pragma unroll
        for (int i = 0; i < 9; ++i) {
            int off = (i * 256 + tid) * 16;
            *(f32x4*)(sRaw + off) = *(const f32x4*)(ws + off);
        }
    } else {
        _Float16* h = (_Float16*)sRaw;
        float*    f = (float*)sRaw;
        for (int i = tid; i < 16384; i += 256) {
            int k = i >> 7, n2 = i & 127;
            float wv = W2g[i];
            int s = k >> 5, hi = (k >> 4) & 1, qq = (k >> 2) & 3, c = k & 3;
            int kp = s * 32 + qq * 8 + hi * 4 + c;
            h[n2 * 128 + (kp ^ ((n2 & 7) << 3))] = (_Float16)wv;
        }
        for (int i = tid; i < 512; i += 256) {
            int j = i & 3, l2 = (i >> 2) & 15, nt = i >> 6;
            h[16384 + i] = (_Float16)W1g[j * 128 + nt * 16 + l2];
        }
        for (int i = tid; i < 768; i += 256) {
            int j = i & 7, t2 = i >> 3;
            int q2 = t2 & 3, u = t2 >> 2;
            int l2 = u % 6, s = u / 6;
            int k = s * 32 + ((j >> 2) << 4) + q2 * 4 + (j & 3);
            h[16896 + i] = (_Float16)W3g[k * 6 + l2];
        }
        if (tid < 128) { f[8832 + tid] = b1g[tid]; f[8960 + tid] = b2g[tid]; }
    }
    // b3 per-lane regs
    float b3c[4];
    #pragma unroll
    for (int r = 0; r < 4; ++r) {
        int n3 = 4 * q + r;
        b3c[r] = (n3 < 6) ? b3g[n3] : 0.0f;
    }

    // ---- prefetch both tiles' inputs (q==0 lanes) ----
    const int base0 = blockIdx.x * 256 + w * 32;   // tile0 rows; tile1 = +128
    half8 bf1[2][2] = {{{}, {}}, {{}, {}}};
    if (q == 0) {
        #pragma unroll
        for (int t2 = 0; t2 < 2; ++t2) {
            #pragma unroll
            for (int mt = 0; mt < 2; ++mt) {
                int m = base0 + t2 * 128 + mt * 16 + ln;
                bf1[t2][mt][0] = (_Float16)tg[m];
                bf1[t2][mt][1] = (_Float16)blg[3 * m + 0];
                bf1[t2][mt][2] = (_Float16)blg[3 * m + 1];
                bf1[t2][mt][3] = (_Float16)blg[3 * m + 2];
            }
        }
    }

    __syncthreads();

    #pragma unroll
    for (int tt = 0; tt < 2; ++tt) {
        // ---- layer 1: C-init = b1 frag ----
        f32x4 acc1[2][8];
        #pragma unroll
        for (int nt = 0; nt < 8; ++nt) {
            half8 a1 = {};
            if (q == 0) {
                half4 lo = *(const half4*)&sW1[nt * 64 + ln * 4];
                a1[0] = lo[0]; a1[1] = lo[1]; a1[2] = lo[2]; a1[3] = lo[3];
            }
            f32x4 bb = *(const f32x4*)&sB1[nt * 16 + 4 * q];
            acc1[0][nt] = __builtin_amdgcn_mfma_f32_16x16x32_f16(a1, bf1[tt][0], bb, 0, 0, 0);
            acc1[1][nt] = __builtin_amdgcn_mfma_f32_16x16x32_f16(a1, bf1[tt][1], bb, 0, 0, 0);
        }

        // ---- epilogue 1: silu only ----
        half8 bf2[2][4];
        #pragma unroll
        for (int mt = 0; mt < 2; ++mt) {
            #pragma unroll
            for (int s = 0; s < 4; ++s) {
                Half8U u;
                #pragma unroll
                for (int hj = 0; hj < 2; ++hj) {
                    int nt = 2 * s + hj;
                    u.h2[hj * 2 + 0] = silu2(acc1[mt][nt][0], acc1[mt][nt][1]);
                    u.h2[hj * 2 + 1] = silu2(acc1[mt][nt][2], acc1[mt][nt][3]);
                }
                bf2[mt][s] = u.v;
            }
        }

        // ---- layer 2: C-init = b2 frag at s==0 ----
        f32x4 acc2[2][8];
        #pragma unroll
        for (int s = 0; s < 4; ++s) {
            #pragma unroll
            for (int nt = 0; nt < 8; ++nt) {
                int n2 = nt * 16 + ln;
                int hw = n2 * 128 + ((s * 32 + q * 8) ^ ((n2 & 7) << 3));
                half8 a2 = *(const half8*)&sW2[hw];
                if (s == 0) {
                    f32x4 bb = *(const f32x4*)&sB2[nt * 16 + 4 * q];
                    acc2[0][nt] = __builtin_amdgcn_mfma_f32_16x16x32_f16(a2, bf2[0][0], bb, 0, 0, 0);
                    acc2[1][nt] = __builtin_amdgcn_mfma_f32_16x16x32_f16(a2, bf2[1][0], bb, 0, 0, 0);
                } else {
                    acc2[0][nt] = __builtin_amdgcn_mfma_f32_16x16x32_f16(a2, bf2[0][s], acc2[0][nt], 0, 0, 0);
                    acc2[1][nt] = __builtin_amdgcn_mfma_f32_16x16x32_f16(a2, bf2[1][s], acc2[1][nt], 0, 0, 0);
                }
            }
        }

        // ---- epilogue 2: silu only ----
        half8 bf3[2][4];
        #pragma unroll
        for (int mt = 0; mt < 2; ++mt) {
            #pragma unroll
            for (int s = 0; s < 4; ++s) {
                Half8U u;
                #pragma unroll
                for (int hj = 0; hj < 2; ++hj) {
                    int nt = 2 * s + hj;
                    u.h2[hj * 2 + 0] = silu2(acc2[mt][nt][0], acc2[mt][nt][1]);
                    u.h2[hj * 2 + 1] = silu2(acc2[mt][nt][2], acc2[mt][nt][3]);
                }
                bf3[mt][s] = u.v;
            }
        }

        // ---- layer 3: C-init = b3 regs ----
        f32x4 acc3[2];
        acc3[0] = (f32x4){b3c[0], b3c[1], b3c[2], b3c[3]};
        acc3[1] = (f32x4){b3c[0], b3c[1], b3c[2], b3c[3]};
        #pragma unroll
        for (int s = 0; s < 4; ++s) {
            half8 a3 = {};
            if (ln < 6) a3 = *(const half8*)&sW3[((s * 6 + ln) * 4 + q) * 8];
            acc3[0] = __builtin_amdgcn_mfma_f32_16x16x32_f16(a3, bf3[0][s], acc3[0], 0, 0, 0);
            acc3[1] = __builtin_amdgcn_mfma_f32_16x16x32_f16(a3, bf3[1][s], acc3[1], 0, 0, 0);
        }

        // ---- epilogue 3: pack params fp16 -> LDS (stride-3 dwords) ----
        #pragma unroll
        for (int mt = 0; mt < 2; ++mt) {
            int row = tt * 32 + mt * 16 + ln;
            if (q == 0) {
                sPU[row * 3 + 0] = pk16(acc3[mt][0], acc3[mt][1]);  // th1, ph1
                sPU[row * 3 + 1] = pk16(acc3[mt][2], acc3[mt][3]);  // th2, ph2
            } else if (q == 1) {
                sPU[row * 3 + 2] = pk16(acc3[mt][0], acc3[mt][1]);  // th3, ph3
            }
        }
    }
    DSFENCE();   // wave-private: params visible to all lanes

    // ---- circuit sim: 64 rows across 64 lanes ----
    {
        half2 h0 = __builtin_bit_cast(half2, sPU[lane * 3 + 0]);
        half2 h1 = __builtin_bit_cast(half2, sPU[lane * 3 + 1]);
        half2 h2 = __builtin_bit_cast(half2, sPU[lane * 3 + 2]);
        float pr[6] = {(float)h0[0], (float)h0[1], (float)h1[0],
                       (float)h1[1], (float)h2[0], (float)h2[1]};
        float ar = 1.f, ai = 0.f, br = 0.f, bi = 0.f;
        #pragma unroll
        for (int l = 0; l < 3; ++l) {
            float th = pr[2 * l] * 0.5f;
            float ph = pr[2 * l + 1] * 0.5f;
            float s1, c1, se, ce;
            __sincosf(th, &s1, &c1);
            float a1r = c1 * ar - s1 * br, a1i = c1 * ai - s1 * bi;
            float b1r = s1 * ar + c1 * br, b1i = s1 * ai + c1 * bi;
            __sincosf(ph, &se, &ce);
            ar = ce * a1r + se * a1i; ai = ce * a1i - se * a1r;
            br = ce * b1r - se * b1i; bi = ce * b1i + se * b1r;
        }
        // same-lane same-address: LDS ops are ordered within a lane
        sPF[lane * 3 + 0] = 2.f * (ar * br + ai * bi);
        sPF[lane * 3 + 1] = 2.f * (ar * bi - ai * br);
        sPF[lane * 3 + 2] = ar * ar + ai * ai - br * br - bi * bi;
    }
    DSFENCE();   // outputs visible cross-lane

    // ---- coalesced stores: 96 floats per tile-half, 48-lane dwordx2 ----
    if (lane < 48) {
        f32x2 v0 = *(const f32x2*)&sPF[2 * lane];
        *(f32x2*)&out[3 * base0 + 2 * lane] = v0;                  // tile 0
        f32x2 v1 = *(const f32x2*)&sPF[96 + 2 * lane];
        *(f32x2*)&out[3 * (base0 + 128) + 2 * lane] = v1;          // tile 1
    }
}

extern "C" void kernel_launch(void* const* d_in, const int* in_sizes, int n_in,
                              void* d_out, int out_size, void* d_ws, size_t ws_size,
                              hipStream_t stream) {
    const float* t  = (const float*)d_in[0];
    const float* bl = (const float*)d_in[1];
    const float* W1 = (const float*)d_in[2];
    const float* b1 = (const float*)d_in[3];
    const float* W2 = (const float*)d_in[4];
    const float* b2 = (const float*)d_in[5];
    const float* W3 = (const float*)d_in[6];
    const float* b3 = (const float*)d_in[7];
    float* out = (float*)d_out;

    if (ws_size >= WS_IMG_BYTES) {
        unsigned char* ws = (unsigned char*)d_ws;
        qvf_pack<<<65, 256, 0, stream>>>(W1, b1, W2, b2, W3, b3, ws);
        qvf_kernel<true><<<NBLOCKS, 256, 0, stream>>>(t, bl, W1, b1, W2, b2, W3, b3, ws, out);
    } else {
        qvf_kernel<false><<<NBLOCKS, 256, 0, stream>>>(t, bl, W1, b1, W2, b2, W3, b3, nullptr, out);
    }
}